// Round 7
// baseline (963.557 us; speedup 1.0000x reference)
//
#include <hip/hip_runtime.h>
#include <hip/hip_bf16.h>
#include <math.h>

#define NNODES 8000
#define NP1    8001
#define H      256
#define CAP    64
#define TSTEPS 8
#define MTOT   (2*NP1)    // 16002
#define MPAD   16128      // 63 * 256
#define NRB    (MPAD/32)  // 504

typedef __attribute__((ext_vector_type(8))) short short8;
typedef __attribute__((ext_vector_type(4))) float floatx4;

__device__ __forceinline__ float bl2f(unsigned short u) {
  union { unsigned int i; float f; } z; z.i = ((unsigned int)u) << 16; return z.f;
}
__device__ __forceinline__ unsigned short f2bl(float f) {
  __hip_bfloat16 b = __float2bfloat16(f);
  return *(unsigned short*)&b;
}
__device__ __forceinline__ float sigf(float x) { return 1.f / (1.f + __expf(-x)); }
__device__ __forceinline__ float tanhf_fast(float x) { return 2.f / (1.f + __expf(-2.f * x)) - 1.f; }

// ------- build ELL: wave-per-row ballot compaction (env-limited ~158 us) -----------
__global__ __launch_bounds__(256) void build_ell_kernel(
    const float* __restrict__ adj_b, const float* __restrict__ adj_a,
    int* __restrict__ counts, int* __restrict__ colidx)
{
  int w = threadIdx.x >> 6, l = threadIdx.x & 63;
  int b = blockIdx.x * 4 + w;     // grid 4000 -> b < 16000
  int g = b >= NNODES;
  int row = b - g * NNODES;
  const float* adj = (g ? adj_a : adj_b) + (size_t)row * NNODES;
  unsigned long long lt = (1ull << l) - 1;
  int base = 0;
  int* dst = colidx + (size_t)b * CAP;

  #define SLOT(vec, u, colv) { \
    bool nz = (&vec.x)[u] != 0.f; \
    unsigned long long m = __ballot(nz); \
    if (nz) { int idx = base + (int)__popcll(m & lt); if (idx < CAP) dst[idx] = (colv); } \
    base += (int)__popcll(m); }
  #define GROUP(vec, cb) { \
    bool any4 = ((&vec.x)[0] != 0.f) | ((&vec.x)[1] != 0.f) | \
                ((&vec.x)[2] != 0.f) | ((&vec.x)[3] != 0.f); \
    if (__ballot(any4)) { \
      SLOT(vec, 0, (cb) + 0) SLOT(vec, 1, (cb) + 1) \
      SLOT(vec, 2, (cb) + 2) SLOT(vec, 3, (cb) + 3) } }

  for (int c0 = l * 4; c0 < NNODES; c0 += 1024) {
    int c1 = c0 + 256, c2 = c0 + 512, c3 = c0 + 768;
    bool p1 = c1 < NNODES, p2 = c2 < NNODES, p3 = c3 < NNODES;
    float4 v0 = *(const float4*)(adj + c0);
    float4 v1 = p1 ? *(const float4*)(adj + c1) : make_float4(0,0,0,0);
    float4 v2 = p2 ? *(const float4*)(adj + c2) : make_float4(0,0,0,0);
    float4 v3 = p3 ? *(const float4*)(adj + c3) : make_float4(0,0,0,0);
    GROUP(v0, c0) GROUP(v1, c1) GROUP(v2, c2) GROUP(v3, c3)
  }
  #undef GROUP
  #undef SLOT
  if (l == 0) counts[b] = base < CAP ? base : CAP;
}

// ---------------- degf[row] for row-space [MPAD] -----------------------------------
__global__ __launch_bounds__(256) void degf_kernel(
    const int* __restrict__ counts, float* __restrict__ degf)
{
  int row = blockIdx.x * 256 + threadIdx.x;   // grid 63
  float d = 0.f;
  if (row < MTOT) {
    int g = row >= NP1;
    int r = row - g * NP1;
    if (r < NNODES) d = (float)counts[g * NNODES + r];
    else if (r == NNODES) d = (float)NNODES;
  }
  degf[row] = d;
}

// ---- Wbig2 [768,512] bf16, n-packed gate-interleave; bc = W_ih @ b_lin ------------
// Row p: ct32=p/96, gb=(p%96)>>4 (0..5), u=p&15; jj=gb>>1 (gate r,z,n), uh=gb&1.
// unit c = ct32*32 + uh*16 + u; gr = jj*256 + c.
// Row content: [0:256]=(Wih@Wlin)[gr], [256:512]=Whh[gr].
__global__ __launch_bounds__(256) void weights_kernel(
    const float* __restrict__ Wih, const float* __restrict__ Wlin,
    const float* __restrict__ blin, const float* __restrict__ Whh,
    __hip_bfloat16* __restrict__ Wbig2, float* __restrict__ bc)
{
  __shared__ float srow[H];
  __shared__ float red[256];
  int p = blockIdx.x;             // 0..767
  int ct32 = p / 96, w96 = p - ct32 * 96;
  int gb = w96 >> 4, u = w96 & 15;
  int jj = gb >> 1, uh = gb & 1;
  int c = ct32 * 32 + uh * 16 + u;
  int gr = jj * 256 + c;
  int t = threadIdx.x;
  size_t ob = (size_t)p * 512;
  srow[t] = Wih[(size_t)gr * H + t];
  __syncthreads();
  float acc = 0.f;
  #pragma unroll 8
  for (int k = 0; k < H; ++k) acc += srow[k] * Wlin[(size_t)k * H + t];
  Wbig2[ob + t] = __float2bfloat16(acc);
  Wbig2[ob + 256 + t] = __float2bfloat16(Whh[(size_t)gr * H + t]);
  red[t] = srow[t] * blin[t];
  __syncthreads();
  for (int s = 128; s > 0; s >>= 1) { if (t < s) red[t] += red[t + s]; __syncthreads(); }
  if (t == 0) bc[gr] = red[0];
}

// ---------------- init h (fp32 + bf16) over MPAD rows, colsum -> cs0 ---------------
__global__ __launch_bounds__(256) void init_h_kernel(
    const float* __restrict__ bx, const float* __restrict__ ax,
    float* __restrict__ h, __hip_bfloat16* __restrict__ hbf, float* __restrict__ cs0)
{
  int b = blockIdx.x;             // 0..503
  int t = threadIdx.x;
  float l0 = 0.f, l1 = 0.f;
  for (int q = 0; q < 32; ++q) {
    int row = b * 32 + q;
    int g = row >= NP1;
    int r = row - g * NP1;
    float v = 0.f;
    if (r < NNODES) {
      v = (g ? ax : bx)[(size_t)r * H + t];
      if (g) l1 += v; else l0 += v;
    }
    size_t off = (size_t)row * H + t;
    h[off] = v;
    hbf[off] = __float2bfloat16(v);
  }
  if (l0 != 0.f) atomicAdd(&cs0[t], l0);
  if (l1 != 0.f) atomicAdd(&cs0[256 + t], l1);
}

// ---------------- hagg_bf = bf16(A @ h): wave-per-row, shfl-broadcast cols ---------
__global__ __launch_bounds__(256) void spmm_kernel(
    const unsigned short* __restrict__ hbf, unsigned short* __restrict__ haggbf,
    const int* __restrict__ counts, const int* __restrict__ colidx,
    const float* __restrict__ cs)
{
  int w = threadIdx.x >> 6, l = threadIdx.x & 63;
  int b = blockIdx.x * 4 + w;     // grid 4001
  if (b >= MTOT) return;
  int g = b >= NP1;
  int r = b - g * NP1;
  size_t outoff = (size_t)b * H + l * 4;
  if (r == NNODES) {
    float4 v = *(const float4*)&cs[g * H + l * 4];
    ushort4 o; o.x = f2bl(v.x); o.y = f2bl(v.y); o.z = f2bl(v.z); o.w = f2bl(v.w);
    *(ushort4*)(haggbf + outoff) = o;
    return;
  }
  int rb = g * NNODES + r;
  int cnt = counts[rb];
  const int* cols = colidx + (size_t)rb * CAP;
  // one coalesced load of the whole edge list, then shfl-broadcast
  int c_l = (l < cnt) ? cols[l] : 0;
  const unsigned short* hg = hbf + (size_t)g * NP1 * H;
  float a0 = 0.f, a1 = 0.f, a2 = 0.f, a3 = 0.f;
  int k = 0;
  for (; k + 4 <= cnt; k += 4) {
    int c0 = __shfl(c_l, k), c1 = __shfl(c_l, k + 1);
    int c2 = __shfl(c_l, k + 2), c3 = __shfl(c_l, k + 3);
    uint2 x0 = *(const uint2*)(hg + (size_t)c0 * H + l * 4);
    uint2 x1 = *(const uint2*)(hg + (size_t)c1 * H + l * 4);
    uint2 x2 = *(const uint2*)(hg + (size_t)c2 * H + l * 4);
    uint2 x3 = *(const uint2*)(hg + (size_t)c3 * H + l * 4);
    a0 += bl2f(x0.x & 0xffff) + bl2f(x1.x & 0xffff) + bl2f(x2.x & 0xffff) + bl2f(x3.x & 0xffff);
    a1 += bl2f(x0.x >> 16)    + bl2f(x1.x >> 16)    + bl2f(x2.x >> 16)    + bl2f(x3.x >> 16);
    a2 += bl2f(x0.y & 0xffff) + bl2f(x1.y & 0xffff) + bl2f(x2.y & 0xffff) + bl2f(x3.y & 0xffff);
    a3 += bl2f(x0.y >> 16)    + bl2f(x1.y >> 16)    + bl2f(x2.y >> 16)    + bl2f(x3.y >> 16);
  }
  for (; k < cnt; ++k) {
    int c = __shfl(c_l, k);
    uint2 x = *(const uint2*)(hg + (size_t)c * H + l * 4);
    a0 += bl2f(x.x & 0xffff); a1 += bl2f(x.x >> 16);
    a2 += bl2f(x.y & 0xffff); a3 += bl2f(x.y >> 16);
  }
  ushort4 o; o.x = f2bl(a0); o.y = f2bl(a1); o.z = f2bl(a2); o.w = f2bl(a3);
  *(ushort4*)(haggbf + outoff) = o;
}

// ------- fused [hagg|h] @ Wbig2^T (bf16 MFMA, K=512) + GRU epilogue ----------------
// 256 rows x 32 units, B-tile 96 rows (n-packed). XCD-pinned grid 512.
// DOUBLE-BUFFERED single-barrier K-loop: stage(k+1) is issued right after the
// barrier and consumed one full compute phase later, so the implicit vmcnt(0)
// in the next __syncthreads finds the DMA already landed (no hot drain).
// acc slots: 0=r(ir+hr), 1=z(iz+hz), 2=in (i-phase), 3=hn (h-phase).
__global__ __launch_bounds__(256, 2) void fused_gemm_gru_kernel(
    const __hip_bfloat16* __restrict__ haggbf, const __hip_bfloat16* __restrict__ hin,
    const __hip_bfloat16* __restrict__ Wbig2, const float* __restrict__ degf,
    const float* __restrict__ bc, const float* __restrict__ bih,
    const float* __restrict__ bhh,
    float* __restrict__ h, __hip_bfloat16* __restrict__ hout,
    float* __restrict__ cs_next)
{
  __shared__ __align__(16) short lsA[2][256 * 32];   // 32 KB
  __shared__ __align__(16) short lsB[2][96 * 32];    // 12 KB
  int bidx = blockIdx.x;                   // 0..511
  int ct = bidx >> 6;                      // 0..7
  int m_i = bidx & 63;                     // 0..63 (63 == idle pad)
  if (m_i >= 63) return;
  int m0 = m_i * 256;
  const short* Bbase = (const short*)Wbig2 + (size_t)ct * 96 * 512;
  const short* Ai = (const short*)haggbf;
  const short* Ah = (const short*)hin;
  int t = threadIdx.x;
  int w = t >> 6, l = t & 63;
  int lr = l >> 2, lc = l & 3;
  int wm = (w & 1) * 128, uh = w >> 1;
  int q = l >> 4, lm = l & 15;
  floatx4 acc[8][4] = {};

  #define STAGE(ks) { \
    int buf_ = (ks) & 1; \
    int k0_ = (ks) * 32; \
    const short* Asrc_ = (k0_ < 256) ? Ai : Ah; \
    int ka_ = k0_ & 255; \
    _Pragma("unroll") \
    for (int j = 0; j < 4; ++j) { \
      int r_ = w * 64 + j * 16 + lr; \
      int cch_ = lc ^ ((r_ >> 1) & 3); \
      const short* ga_ = Asrc_ + (size_t)(m0 + r_) * H + ka_ + cch_ * 8; \
      short* la_ = &lsA[buf_][(w * 64 + j * 16) * 32]; \
      __builtin_amdgcn_global_load_lds((const __attribute__((address_space(1))) void*)ga_, \
                                       (__attribute__((address_space(3))) void*)la_, 16, 0, 0); \
    } \
    if (w < 3) { \
      _Pragma("unroll") \
      for (int j = 0; j < 2; ++j) { \
        int r_ = (w * 2 + j) * 16 + lr; \
        int cch_ = lc ^ ((r_ >> 1) & 3); \
        const short* gb_ = Bbase + (size_t)r_ * 512 + k0_ + cch_ * 8; \
        short* lb_ = &lsB[buf_][(w * 2 + j) * 16 * 32]; \
        __builtin_amdgcn_global_load_lds((const __attribute__((address_space(1))) void*)gb_, \
                                         (__attribute__((address_space(3))) void*)lb_, 16, 0, 0); \
      } \
    } }

  STAGE(0)
  #pragma unroll 4
  for (int ks = 0; ks < 16; ++ks) {
    __syncthreads();                 // vmcnt(0) here is cheap: stage(ks) is a full phase old
    if (ks < 15) STAGE(ks + 1)
    int buf = ks & 1;
    bool ihalf = ks < 8;
    short8 bfr[3];
    #pragma unroll
    for (int jj = 0; jj < 3; ++jj) {
      int n = (jj * 2 + uh) * 16 + lm;
      bfr[jj] = *(const short8*)&lsB[buf][n * 32 + (q ^ ((n >> 1) & 3)) * 8];
    }
    #pragma unroll
    for (int i = 0; i < 8; ++i) {
      int m = wm + i * 16 + lm;
      short8 af = *(const short8*)&lsA[buf][m * 32 + (q ^ ((m >> 1) & 3)) * 8];
      acc[i][0] = __builtin_amdgcn_mfma_f32_16x16x32_bf16(af, bfr[0], acc[i][0], 0, 0, 0);
      acc[i][1] = __builtin_amdgcn_mfma_f32_16x16x32_bf16(af, bfr[1], acc[i][1], 0, 0, 0);
      if (ihalf)
        acc[i][2] = __builtin_amdgcn_mfma_f32_16x16x32_bf16(af, bfr[2], acc[i][2], 0, 0, 0);
      else
        acc[i][3] = __builtin_amdgcn_mfma_f32_16x16x32_bf16(af, bfr[2], acc[i][3], 0, 0, 0);
    }
  }
  #undef STAGE

  // ---- GRU epilogue: lane owns unit c, rows wm+i*16+q*4+reg ----
  int c = ct * 32 + uh * 16 + lm;
  float bcr = bc[c], bcz = bc[256 + c], bcn = bc[512 + c];
  float br  = bih[c] + bhh[c];
  float bz  = bih[256 + c] + bhh[256 + c];
  float bin = bih[512 + c];
  float bhn = bhh[512 + c];
  float lu0 = 0.f, lu1 = 0.f;
  #pragma unroll
  for (int i = 0; i < 8; ++i) {
    int row0 = m0 + wm + i * 16 + q * 4;
    float4 dg = *(const float4*)&degf[row0];
    #pragma unroll
    for (int reg = 0; reg < 4; ++reg) {
      int row = row0 + reg;
      float deg = (&dg.x)[reg];
      float rg = sigf(acc[i][0][reg] + deg * bcr + br);
      float z  = sigf(acc[i][1][reg] + deg * bcz + bz);
      float n  = tanhf_fast(acc[i][2][reg] + deg * bcn + bin + rg * (acc[i][3][reg] + bhn));
      size_t hoff = (size_t)row * H + c;
      float hp = h[hoff];
      float hnew = (1.f - z) * n + z * hp;
      h[hoff] = hnew;
      hout[hoff] = __float2bfloat16(hnew);
      if (row < NP1) { if (row < NNODES) lu0 += hnew; }
      else { if (row - NP1 < NNODES) lu1 += hnew; }
    }
  }
  // 4 lanes (q=0..3) share c: shuffle-reduce, then 1 atomic per group
  lu0 += __shfl_down(lu0, 32); lu0 += __shfl_down(lu0, 16);
  lu1 += __shfl_down(lu1, 32); lu1 += __shfl_down(lu1, 16);
  if (q == 0) {
    if (lu0 != 0.f) atomicAdd(&cs_next[c], lu0);
    if (lu1 != 0.f) atomicAdd(&cs_next[256 + c], lu1);
  }
}

// ---------------- final logits + log_softmax ---------------------------------------
__global__ __launch_bounds__(256) void final_kernel(
    const float* __restrict__ h, const float* __restrict__ Wfc,
    const float* __restrict__ bfc, float* __restrict__ out)
{
  __shared__ float red0[256];
  __shared__ float red1[256];
  int t = threadIdx.x;
  float sn0 = h[(size_t)NNODES * H + t];
  float sn1 = h[((size_t)NP1 + NNODES) * H + t];
  red0[t] = sn0 * Wfc[t]       + sn1 * Wfc[H + t];
  red1[t] = sn0 * Wfc[512 + t] + sn1 * Wfc[512 + H + t];
  __syncthreads();
  for (int s = 128; s > 0; s >>= 1) {
    if (t < s) { red0[t] += red0[t + s]; red1[t] += red1[t + s]; }
    __syncthreads();
  }
  if (t == 0) {
    float l0 = red0[0] + bfc[0], l1 = red1[0] + bfc[1];
    float m = fmaxf(l0, l1);
    float lse = m + logf(expf(l0 - m) + expf(l1 - m));
    out[0] = l0 - lse;
    out[1] = l1 - lse;
  }
}

extern "C" void kernel_launch(void* const* d_in, const int* in_sizes, int n_in,
                              void* d_out, int out_size, void* d_ws, size_t ws_size,
                              hipStream_t stream) {
  const float* b_x   = (const float*)d_in[0];
  const float* b_adj = (const float*)d_in[1];
  const float* a_x   = (const float*)d_in[2];
  const float* a_adj = (const float*)d_in[3];
  const float* Wlin  = (const float*)d_in[4];
  const float* blin  = (const float*)d_in[5];
  const float* Wih   = (const float*)d_in[6];
  const float* bih   = (const float*)d_in[7];
  const float* Whh   = (const float*)d_in[8];
  const float* bhh   = (const float*)d_in[9];
  const float* Wfc   = (const float*)d_in[10];
  const float* bfc   = (const float*)d_in[11];
  float* out = (float*)d_out;

  char* ws = (char*)d_ws;
  size_t off = 0;
  auto alloc = [&](size_t bytes) {
    void* p = ws + off;
    off += (bytes + 255) & ~(size_t)255;
    return p;
  };
  float* h               = (float*)alloc((size_t)MPAD * H * 4);            // 16.5 MB
  __hip_bfloat16* hbf0   = (__hip_bfloat16*)alloc((size_t)MPAD * H * 2);   // 8.3 MB
  __hip_bfloat16* hbf1   = (__hip_bfloat16*)alloc((size_t)MPAD * H * 2);   // 8.3 MB
  __hip_bfloat16* haggbf = (__hip_bfloat16*)alloc((size_t)MPAD * H * 2);   // 8.3 MB
  __hip_bfloat16* Wbig2  = (__hip_bfloat16*)alloc((size_t)768 * 512 * 2);  // 0.8 MB
  float* bc              = (float*)alloc((size_t)768 * 4);
  int* colidx            = (int*)alloc((size_t)2 * NNODES * CAP * 4);      // 4.1 MB
  int* counts            = (int*)alloc((size_t)2 * NNODES * 4 + 1024);
  float* degf            = (float*)alloc((size_t)MPAD * 4);
  float* cs              = (float*)alloc((size_t)(TSTEPS + 1) * 2 * H * 4);

  hipMemsetAsync(cs, 0, (size_t)(TSTEPS + 1) * 2 * H * 4, stream);

  build_ell_kernel<<<4000, 256, 0, stream>>>(b_adj, a_adj, counts, colidx);
  degf_kernel<<<MPAD / 256, 256, 0, stream>>>(counts, degf);
  weights_kernel<<<768, 256, 0, stream>>>(Wih, Wlin, blin, Whh, Wbig2, bc);
  init_h_kernel<<<NRB, 256, 0, stream>>>(b_x, a_x, h, hbf0, cs);

  __hip_bfloat16* ping[2] = { hbf0, hbf1 };
  for (int t = 0; t < TSTEPS; ++t) {
    __hip_bfloat16* hin  = ping[t & 1];
    __hip_bfloat16* hout = ping[(t + 1) & 1];
    spmm_kernel<<<(MTOT + 3) / 4, 256, 0, stream>>>(
        (const unsigned short*)hin, (unsigned short*)haggbf, counts, colidx, cs + t * 2 * H);
    fused_gemm_gru_kernel<<<512, 256, 0, stream>>>(
        haggbf, hin, Wbig2, degf, bc, bih, bhh, h, hout, cs + (t + 1) * 2 * H);
  }
  final_kernel<<<1, 256, 0, stream>>>(h, Wfc, bfc, out);
}

// Round 8
// 886.629 us; speedup vs baseline: 1.0868x; 1.0868x over previous
//
#include <hip/hip_runtime.h>
#include <hip/hip_bf16.h>
#include <math.h>

#define NNODES 8000
#define NP1    8001
#define H      256
#define CAP    64
#define TSTEPS 8
#define MTOT   (2*NP1)    // 16002
#define MPAD   16128      // 63 * 256
#define NRB    (MPAD/32)  // 504

typedef __attribute__((ext_vector_type(8))) short short8;
typedef __attribute__((ext_vector_type(4))) float floatx4;

__device__ __forceinline__ float bl2f(unsigned short u) {
  union { unsigned int i; float f; } z; z.i = ((unsigned int)u) << 16; return z.f;
}
__device__ __forceinline__ unsigned short f2bl(float f) {
  __hip_bfloat16 b = __float2bfloat16(f);
  return *(unsigned short*)&b;
}
__device__ __forceinline__ float sigf(float x) { return 1.f / (1.f + __expf(-x)); }
__device__ __forceinline__ float tanhf_fast(float x) { return 2.f / (1.f + __expf(-2.f * x)) - 1.f; }

// ------- build ELL: wave-per-row ballot compaction (env-limited ~158 us) -----------
__global__ __launch_bounds__(256) void build_ell_kernel(
    const float* __restrict__ adj_b, const float* __restrict__ adj_a,
    int* __restrict__ counts, int* __restrict__ colidx)
{
  int w = threadIdx.x >> 6, l = threadIdx.x & 63;
  int b = blockIdx.x * 4 + w;     // grid 4000 -> b < 16000
  int g = b >= NNODES;
  int row = b - g * NNODES;
  const float* adj = (g ? adj_a : adj_b) + (size_t)row * NNODES;
  unsigned long long lt = (1ull << l) - 1;
  int base = 0;
  int* dst = colidx + (size_t)b * CAP;

  #define SLOT(vec, u, colv) { \
    bool nz = (&vec.x)[u] != 0.f; \
    unsigned long long m = __ballot(nz); \
    if (nz) { int idx = base + (int)__popcll(m & lt); if (idx < CAP) dst[idx] = (colv); } \
    base += (int)__popcll(m); }
  #define GROUP(vec, cb) { \
    bool any4 = ((&vec.x)[0] != 0.f) | ((&vec.x)[1] != 0.f) | \
                ((&vec.x)[2] != 0.f) | ((&vec.x)[3] != 0.f); \
    if (__ballot(any4)) { \
      SLOT(vec, 0, (cb) + 0) SLOT(vec, 1, (cb) + 1) \
      SLOT(vec, 2, (cb) + 2) SLOT(vec, 3, (cb) + 3) } }

  for (int c0 = l * 4; c0 < NNODES; c0 += 1024) {
    int c1 = c0 + 256, c2 = c0 + 512, c3 = c0 + 768;
    bool p1 = c1 < NNODES, p2 = c2 < NNODES, p3 = c3 < NNODES;
    float4 v0 = *(const float4*)(adj + c0);
    float4 v1 = p1 ? *(const float4*)(adj + c1) : make_float4(0,0,0,0);
    float4 v2 = p2 ? *(const float4*)(adj + c2) : make_float4(0,0,0,0);
    float4 v3 = p3 ? *(const float4*)(adj + c3) : make_float4(0,0,0,0);
    GROUP(v0, c0) GROUP(v1, c1) GROUP(v2, c2) GROUP(v3, c3)
  }
  #undef GROUP
  #undef SLOT
  if (l == 0) counts[b] = base < CAP ? base : CAP;
}

// ---------------- degf[row] for row-space [MPAD] -----------------------------------
__global__ __launch_bounds__(256) void degf_kernel(
    const int* __restrict__ counts, float* __restrict__ degf)
{
  int row = blockIdx.x * 256 + threadIdx.x;   // grid 63
  float d = 0.f;
  if (row < MTOT) {
    int g = row >= NP1;
    int r = row - g * NP1;
    if (r < NNODES) d = (float)counts[g * NNODES + r];
    else if (r == NNODES) d = (float)NNODES;
  }
  degf[row] = d;
}

// ---- Wbig2 [768,512] bf16, n-packed gate-interleave; bc = W_ih @ b_lin ------------
__global__ __launch_bounds__(256) void weights_kernel(
    const float* __restrict__ Wih, const float* __restrict__ Wlin,
    const float* __restrict__ blin, const float* __restrict__ Whh,
    __hip_bfloat16* __restrict__ Wbig2, float* __restrict__ bc)
{
  __shared__ float srow[H];
  __shared__ float red[256];
  int p = blockIdx.x;             // 0..767
  int ct32 = p / 96, w96 = p - ct32 * 96;
  int gb = w96 >> 4, u = w96 & 15;
  int jj = gb >> 1, uh = gb & 1;
  int c = ct32 * 32 + uh * 16 + u;
  int gr = jj * 256 + c;
  int t = threadIdx.x;
  size_t ob = (size_t)p * 512;
  srow[t] = Wih[(size_t)gr * H + t];
  __syncthreads();
  float acc = 0.f;
  #pragma unroll 8
  for (int k = 0; k < H; ++k) acc += srow[k] * Wlin[(size_t)k * H + t];
  Wbig2[ob + t] = __float2bfloat16(acc);
  Wbig2[ob + 256 + t] = __float2bfloat16(Whh[(size_t)gr * H + t]);
  red[t] = srow[t] * blin[t];
  __syncthreads();
  for (int s = 128; s > 0; s >>= 1) { if (t < s) red[t] += red[t + s]; __syncthreads(); }
  if (t == 0) bc[gr] = red[0];
}

// ---------------- init h (bf16 only) over MPAD rows, colsum -> cs0 -----------------
__global__ __launch_bounds__(256) void init_h_kernel(
    const float* __restrict__ bx, const float* __restrict__ ax,
    __hip_bfloat16* __restrict__ hbf, float* __restrict__ cs0)
{
  int b = blockIdx.x;             // 0..503
  int t = threadIdx.x;
  float l0 = 0.f, l1 = 0.f;
  for (int q = 0; q < 32; ++q) {
    int row = b * 32 + q;
    int g = row >= NP1;
    int r = row - g * NP1;
    float v = 0.f;
    if (r < NNODES) {
      v = (g ? ax : bx)[(size_t)r * H + t];
      if (g) l1 += v; else l0 += v;
    }
    hbf[(size_t)row * H + t] = __float2bfloat16(v);
  }
  if (l0 != 0.f) atomicAdd(&cs0[t], l0);
  if (l1 != 0.f) atomicAdd(&cs0[256 + t], l1);
}

// ---------------- hagg_bf = bf16(A @ h): wave-per-row gather (round-6 form) --------
__global__ __launch_bounds__(256) void spmm_kernel(
    const unsigned short* __restrict__ hbf, unsigned short* __restrict__ haggbf,
    const int* __restrict__ counts, const int* __restrict__ colidx,
    const float* __restrict__ cs)
{
  int w = threadIdx.x >> 6, l = threadIdx.x & 63;
  int b = blockIdx.x * 4 + w;     // grid 4001
  if (b >= MTOT) return;
  int g = b >= NP1;
  int r = b - g * NP1;
  size_t outoff = (size_t)b * H + l * 4;
  if (r == NNODES) {
    float4 v = *(const float4*)&cs[g * H + l * 4];
    ushort4 o; o.x = f2bl(v.x); o.y = f2bl(v.y); o.z = f2bl(v.z); o.w = f2bl(v.w);
    *(ushort4*)(haggbf + outoff) = o;
    return;
  }
  int rb = g * NNODES + r;
  int cnt = counts[rb];
  const int* cols = colidx + (size_t)rb * CAP;
  const unsigned short* hg = hbf + (size_t)g * NP1 * H;
  float a0 = 0.f, a1 = 0.f, a2 = 0.f, a3 = 0.f;
  int k = 0;
  for (; k + 4 <= cnt; k += 4) {
    int c0 = cols[k], c1 = cols[k+1], c2 = cols[k+2], c3 = cols[k+3];
    uint2 x0 = *(const uint2*)(hg + (size_t)c0 * H + l * 4);
    uint2 x1 = *(const uint2*)(hg + (size_t)c1 * H + l * 4);
    uint2 x2 = *(const uint2*)(hg + (size_t)c2 * H + l * 4);
    uint2 x3 = *(const uint2*)(hg + (size_t)c3 * H + l * 4);
    a0 += bl2f(x0.x & 0xffff) + bl2f(x1.x & 0xffff) + bl2f(x2.x & 0xffff) + bl2f(x3.x & 0xffff);
    a1 += bl2f(x0.x >> 16)    + bl2f(x1.x >> 16)    + bl2f(x2.x >> 16)    + bl2f(x3.x >> 16);
    a2 += bl2f(x0.y & 0xffff) + bl2f(x1.y & 0xffff) + bl2f(x2.y & 0xffff) + bl2f(x3.y & 0xffff);
    a3 += bl2f(x0.y >> 16)    + bl2f(x1.y >> 16)    + bl2f(x2.y >> 16)    + bl2f(x3.y >> 16);
  }
  for (; k < cnt; ++k) {
    uint2 x = *(const uint2*)(hg + (size_t)cols[k] * H + l * 4);
    a0 += bl2f(x.x & 0xffff); a1 += bl2f(x.x >> 16);
    a2 += bl2f(x.y & 0xffff); a3 += bl2f(x.y >> 16);
  }
  ushort4 o; o.x = f2bl(a0); o.y = f2bl(a1); o.z = f2bl(a2); o.w = f2bl(a3);
  *(ushort4*)(haggbf + outoff) = o;
}

// ------- fused [hagg|h] @ Wbig2^T (bf16 MFMA, K=512, BK=64) + GRU epilogue ---------
// 256 rows x 32 units, B-tile 96 rows (n-packed). XCD-pinned grid 512.
// BK=64: 8 k-steps, each 48 MFMAs / 22 ds_read_b128 / 11 DMA / 2 barriers —
// barrier-drain count halved vs BK=32. LDS rows are 128 B (8 chunks of 16 B);
// swizzle applied on GLOBAL source side (chunk c of row r holds global chunk
// c^(r&7)) so DMA dest stays lane-contiguous and frag reads are 2-way (free).
// h state is bf16-only: recurrence reads h_prev from hin (same value the GEMM
// consumed), fp32 h buffer eliminated.
__global__ __launch_bounds__(256, 2) void fused_gemm_gru_kernel(
    const __hip_bfloat16* __restrict__ haggbf, const __hip_bfloat16* __restrict__ hin,
    const __hip_bfloat16* __restrict__ Wbig2, const float* __restrict__ degf,
    const float* __restrict__ bc, const float* __restrict__ bih,
    const float* __restrict__ bhh,
    __hip_bfloat16* __restrict__ hout, float* __restrict__ cs_next)
{
  __shared__ __align__(16) short lsA[256 * 64];   // 32 KB
  __shared__ __align__(16) short lsB[96 * 64];    // 12 KB
  int bidx = blockIdx.x;                   // 0..511
  int ct = bidx >> 6;                      // 0..7
  int m_i = bidx & 63;                     // 0..63 (63 == idle pad)
  if (m_i >= 63) return;
  int m0 = m_i * 256;
  const short* Bbase = (const short*)Wbig2 + (size_t)ct * 96 * 512;
  const short* Ai = (const short*)haggbf;
  const short* Ah = (const short*)hin;
  const unsigned short* hin_us = (const unsigned short*)hin;
  int t = threadIdx.x;
  int w = t >> 6, l = t & 63;
  int lr = l >> 3;        // staging: row within 8-row group
  int lc = l & 7;         // staging: chunk slot (16 B)
  int wm = (w & 1) * 128, uh = w >> 1;
  int q = l >> 4, lm = l & 15;
  floatx4 acc[8][4] = {};

  for (int ks = 0; ks < 8; ++ks) {
    int k0 = ks * 64;
    bool ihalf = ks < 4;
    const short* Asrc = ihalf ? Ai : Ah;
    int ka = k0 & 255;
    // stage A: wave w covers rows w*64 .. w*64+63 (8 insts x 8 rows)
    #pragma unroll
    for (int j = 0; j < 8; ++j) {
      int r = w * 64 + j * 8 + lr;
      int sc = lc ^ (r & 7);
      const short* ga = Asrc + (size_t)(m0 + r) * H + ka + sc * 8;
      short* la = lsA + (w * 64 + j * 8) * 64;
      __builtin_amdgcn_global_load_lds((const __attribute__((address_space(1))) void*)ga,
                                       (__attribute__((address_space(3))) void*)la, 16, 0, 0);
    }
    // stage B: wave w covers rows w*24 .. w*24+23 (3 insts x 8 rows)
    #pragma unroll
    for (int j = 0; j < 3; ++j) {
      int r = w * 24 + j * 8 + lr;
      int sc = lc ^ (r & 7);
      const short* gb = Bbase + (size_t)r * 512 + k0 + sc * 8;
      short* lb = lsB + (w * 24 + j * 8) * 64;
      __builtin_amdgcn_global_load_lds((const __attribute__((address_space(1))) void*)gb,
                                       (__attribute__((address_space(3))) void*)lb, 16, 0, 0);
    }
    __syncthreads();
    #pragma unroll
    for (int kh = 0; kh < 2; ++kh) {
      int kc = kh * 4 + q;
      short8 bfr[3];
      #pragma unroll
      for (int jj = 0; jj < 3; ++jj) {
        int n = (jj * 2 + uh) * 16 + lm;
        bfr[jj] = *(const short8*)&lsB[n * 64 + (kc ^ (n & 7)) * 8];
      }
      #pragma unroll
      for (int i = 0; i < 8; ++i) {
        int m = wm + i * 16 + lm;
        short8 af = *(const short8*)&lsA[m * 64 + (kc ^ (m & 7)) * 8];
        acc[i][0] = __builtin_amdgcn_mfma_f32_16x16x32_bf16(af, bfr[0], acc[i][0], 0, 0, 0);
        acc[i][1] = __builtin_amdgcn_mfma_f32_16x16x32_bf16(af, bfr[1], acc[i][1], 0, 0, 0);
        if (ihalf)
          acc[i][2] = __builtin_amdgcn_mfma_f32_16x16x32_bf16(af, bfr[2], acc[i][2], 0, 0, 0);
        else
          acc[i][3] = __builtin_amdgcn_mfma_f32_16x16x32_bf16(af, bfr[2], acc[i][3], 0, 0, 0);
      }
    }
    __syncthreads();
  }

  // ---- GRU epilogue: lane owns unit c, rows wm+i*16+q*4+reg ----
  int c = ct * 32 + uh * 16 + lm;
  float bcr = bc[c], bcz = bc[256 + c], bcn = bc[512 + c];
  float br  = bih[c] + bhh[c];
  float bz  = bih[256 + c] + bhh[256 + c];
  float bin = bih[512 + c];
  float bhn = bhh[512 + c];
  float lu0 = 0.f, lu1 = 0.f;
  #pragma unroll
  for (int i = 0; i < 8; ++i) {
    int row0 = m0 + wm + i * 16 + q * 4;
    float4 dg = *(const float4*)&degf[row0];
    #pragma unroll
    for (int reg = 0; reg < 4; ++reg) {
      int row = row0 + reg;
      float deg = (&dg.x)[reg];
      float rg = sigf(acc[i][0][reg] + deg * bcr + br);
      float z  = sigf(acc[i][1][reg] + deg * bcz + bz);
      float n  = tanhf_fast(acc[i][2][reg] + deg * bcn + bin + rg * (acc[i][3][reg] + bhn));
      size_t hoff = (size_t)row * H + c;
      float hp = bl2f(hin_us[hoff]);
      float hnew = (1.f - z) * n + z * hp;
      hout[hoff] = __float2bfloat16(hnew);
      if (row < NP1) { if (row < NNODES) lu0 += hnew; }
      else { if (row - NP1 < NNODES) lu1 += hnew; }
    }
  }
  // 4 lanes (q=0..3) share c: shuffle-reduce, then 1 atomic per group
  lu0 += __shfl_down(lu0, 32); lu0 += __shfl_down(lu0, 16);
  lu1 += __shfl_down(lu1, 32); lu1 += __shfl_down(lu1, 16);
  if (q == 0) {
    if (lu0 != 0.f) atomicAdd(&cs_next[c], lu0);
    if (lu1 != 0.f) atomicAdd(&cs_next[256 + c], lu1);
  }
}

// ---------------- final logits + log_softmax (bf16 h state) ------------------------
__global__ __launch_bounds__(256) void final_kernel(
    const unsigned short* __restrict__ hbf, const float* __restrict__ Wfc,
    const float* __restrict__ bfc, float* __restrict__ out)
{
  __shared__ float red0[256];
  __shared__ float red1[256];
  int t = threadIdx.x;
  float sn0 = bl2f(hbf[(size_t)NNODES * H + t]);
  float sn1 = bl2f(hbf[((size_t)NP1 + NNODES) * H + t]);
  red0[t] = sn0 * Wfc[t]       + sn1 * Wfc[H + t];
  red1[t] = sn0 * Wfc[512 + t] + sn1 * Wfc[512 + H + t];
  __syncthreads();
  for (int s = 128; s > 0; s >>= 1) {
    if (t < s) { red0[t] += red0[t + s]; red1[t] += red1[t + s]; }
    __syncthreads();
  }
  if (t == 0) {
    float l0 = red0[0] + bfc[0], l1 = red1[0] + bfc[1];
    float m = fmaxf(l0, l1);
    float lse = m + logf(expf(l0 - m) + expf(l1 - m));
    out[0] = l0 - lse;
    out[1] = l1 - lse;
  }
}

extern "C" void kernel_launch(void* const* d_in, const int* in_sizes, int n_in,
                              void* d_out, int out_size, void* d_ws, size_t ws_size,
                              hipStream_t stream) {
  const float* b_x   = (const float*)d_in[0];
  const float* b_adj = (const float*)d_in[1];
  const float* a_x   = (const float*)d_in[2];
  const float* a_adj = (const float*)d_in[3];
  const float* Wlin  = (const float*)d_in[4];
  const float* blin  = (const float*)d_in[5];
  const float* Wih   = (const float*)d_in[6];
  const float* bih   = (const float*)d_in[7];
  const float* Whh   = (const float*)d_in[8];
  const float* bhh   = (const float*)d_in[9];
  const float* Wfc   = (const float*)d_in[10];
  const float* bfc   = (const float*)d_in[11];
  float* out = (float*)d_out;

  char* ws = (char*)d_ws;
  size_t off = 0;
  auto alloc = [&](size_t bytes) {
    void* p = ws + off;
    off += (bytes + 255) & ~(size_t)255;
    return p;
  };
  __hip_bfloat16* hbf0   = (__hip_bfloat16*)alloc((size_t)MPAD * H * 2);   // 8.3 MB
  __hip_bfloat16* hbf1   = (__hip_bfloat16*)alloc((size_t)MPAD * H * 2);   // 8.3 MB
  __hip_bfloat16* haggbf = (__hip_bfloat16*)alloc((size_t)MPAD * H * 2);   // 8.3 MB
  __hip_bfloat16* Wbig2  = (__hip_bfloat16*)alloc((size_t)768 * 512 * 2);  // 0.8 MB
  float* bc              = (float*)alloc((size_t)768 * 4);
  int* colidx            = (int*)alloc((size_t)2 * NNODES * CAP * 4);      // 4.1 MB
  int* counts            = (int*)alloc((size_t)2 * NNODES * 4 + 1024);
  float* degf            = (float*)alloc((size_t)MPAD * 4);
  float* cs              = (float*)alloc((size_t)(TSTEPS + 1) * 2 * H * 4);

  hipMemsetAsync(cs, 0, (size_t)(TSTEPS + 1) * 2 * H * 4, stream);

  build_ell_kernel<<<4000, 256, 0, stream>>>(b_adj, a_adj, counts, colidx);
  degf_kernel<<<MPAD / 256, 256, 0, stream>>>(counts, degf);
  weights_kernel<<<768, 256, 0, stream>>>(Wih, Wlin, blin, Whh, Wbig2, bc);
  init_h_kernel<<<NRB, 256, 0, stream>>>(b_x, a_x, hbf0, cs);

  __hip_bfloat16* ping[2] = { hbf0, hbf1 };
  for (int t = 0; t < TSTEPS; ++t) {
    __hip_bfloat16* hin  = ping[t & 1];
    __hip_bfloat16* hout = ping[(t + 1) & 1];
    spmm_kernel<<<(MTOT + 3) / 4, 256, 0, stream>>>(
        (const unsigned short*)hin, (unsigned short*)haggbf, counts, colidx, cs + t * 2 * H);
    fused_gemm_gru_kernel<<<512, 256, 0, stream>>>(
        haggbf, hin, Wbig2, degf, bc, bih, bhh, hout, cs + (t + 1) * 2 * H);
  }
  final_kernel<<<1, 256, 0, stream>>>((const unsigned short*)ping[TSTEPS & 1], Wfc, bfc, out);
}

// Round 9
// 878.776 us; speedup vs baseline: 1.0965x; 1.0089x over previous
//
#include <hip/hip_runtime.h>
#include <hip/hip_bf16.h>
#include <math.h>

#define NNODES 8000
#define NP1    8001
#define H      256
#define CAP    64
#define TSTEPS 8
#define MTOT   (2*NP1)    // 16002
#define MPAD   16128      // 63 * 256
#define NRB    (MPAD/32)  // 504

typedef __attribute__((ext_vector_type(8))) short short8;
typedef __attribute__((ext_vector_type(4))) float floatx4;

__device__ __forceinline__ float bl2f(unsigned short u) {
  union { unsigned int i; float f; } z; z.i = ((unsigned int)u) << 16; return z.f;
}
__device__ __forceinline__ unsigned short f2bl(float f) {
  __hip_bfloat16 b = __float2bfloat16(f);
  return *(unsigned short*)&b;
}
__device__ __forceinline__ float sigf(float x) { return 1.f / (1.f + __expf(-x)); }
__device__ __forceinline__ float tanhf_fast(float x) { return 2.f / (1.f + __expf(-2.f * x)) - 1.f; }

// ------- build ELL: lane-per-group scan, ONE branch per 256 cols -------------------
// Old version: ballot+branch per 4-col group = 2000 branch groups/row (issue-bound,
// ~158 us). Now: lane l owns cols [l*4, l*4+4) of each 256-col window; wave-uniform
// skip branch per window (31/row); 4-ballot compaction only in ~16 taken windows.
__global__ __launch_bounds__(256) void build_ell_kernel(
    const float* __restrict__ adj_b, const float* __restrict__ adj_a,
    int* __restrict__ counts, int* __restrict__ colidx)
{
  int w = threadIdx.x >> 6, l = threadIdx.x & 63;
  int b = blockIdx.x * 4 + w;     // grid 4000 -> b < 16000
  int g = b >= NNODES;
  int row = b - g * NNODES;
  const float* adj = (g ? adj_a : adj_b) + (size_t)row * NNODES;
  unsigned long long lt = (1ull << l) - 1;
  int base = 0;
  int* dst = colidx + (size_t)b * CAP;

  // 8000 cols = 31 full windows of 256 + one 64-col tail window
  #pragma unroll 4
  for (int it = 0; it < 32; ++it) {
    int c0 = it * 256 + l * 4;
    float4 v = (c0 < NNODES) ? *(const float4*)(adj + c0) : make_float4(0, 0, 0, 0);
    bool nz0 = v.x != 0.f, nz1 = v.y != 0.f, nz2 = v.z != 0.f, nz3 = v.w != 0.f;
    bool any = nz0 | nz1 | nz2 | nz3;
    if (__ballot(any)) {
      unsigned long long m0 = __ballot(nz0);
      unsigned long long m1 = __ballot(nz1);
      unsigned long long m2 = __ballot(nz2);
      unsigned long long m3 = __ballot(nz3);
      int t0 = (int)__popcll(m0), t1 = (int)__popcll(m1), t2 = (int)__popcll(m2);
      if (nz0) { int i0 = base + (int)__popcll(m0 & lt);           if (i0 < CAP) dst[i0] = c0; }
      if (nz1) { int i1 = base + t0 + (int)__popcll(m1 & lt);      if (i1 < CAP) dst[i1] = c0 + 1; }
      if (nz2) { int i2 = base + t0 + t1 + (int)__popcll(m2 & lt); if (i2 < CAP) dst[i2] = c0 + 2; }
      if (nz3) { int i3 = base + t0 + t1 + t2 + (int)__popcll(m3 & lt); if (i3 < CAP) dst[i3] = c0 + 3; }
      base += t0 + t1 + t2 + (int)__popcll(m3);
    }
  }
  if (l == 0) counts[b] = base < CAP ? base : CAP;
}

// ---------------- degf[row] for row-space [MPAD] -----------------------------------
__global__ __launch_bounds__(256) void degf_kernel(
    const int* __restrict__ counts, float* __restrict__ degf)
{
  int row = blockIdx.x * 256 + threadIdx.x;   // grid 63
  float d = 0.f;
  if (row < MTOT) {
    int g = row >= NP1;
    int r = row - g * NP1;
    if (r < NNODES) d = (float)counts[g * NNODES + r];
    else if (r == NNODES) d = (float)NNODES;
  }
  degf[row] = d;
}

// ---- Wbig2 [768,512] bf16, n-packed gate-interleave; bc = W_ih @ b_lin ------------
__global__ __launch_bounds__(256) void weights_kernel(
    const float* __restrict__ Wih, const float* __restrict__ Wlin,
    const float* __restrict__ blin, const float* __restrict__ Whh,
    __hip_bfloat16* __restrict__ Wbig2, float* __restrict__ bc)
{
  __shared__ float srow[H];
  __shared__ float red[256];
  int p = blockIdx.x;             // 0..767
  int ct32 = p / 96, w96 = p - ct32 * 96;
  int gb = w96 >> 4, u = w96 & 15;
  int jj = gb >> 1, uh = gb & 1;
  int c = ct32 * 32 + uh * 16 + u;
  int gr = jj * 256 + c;
  int t = threadIdx.x;
  size_t ob = (size_t)p * 512;
  srow[t] = Wih[(size_t)gr * H + t];
  __syncthreads();
  float acc = 0.f;
  #pragma unroll 8
  for (int k = 0; k < H; ++k) acc += srow[k] * Wlin[(size_t)k * H + t];
  Wbig2[ob + t] = __float2bfloat16(acc);
  Wbig2[ob + 256 + t] = __float2bfloat16(Whh[(size_t)gr * H + t]);
  red[t] = srow[t] * blin[t];
  __syncthreads();
  for (int s = 128; s > 0; s >>= 1) { if (t < s) red[t] += red[t + s]; __syncthreads(); }
  if (t == 0) bc[gr] = red[0];
}

// ---------------- init h (bf16 only) over MPAD rows, colsum -> cs0 -----------------
__global__ __launch_bounds__(256) void init_h_kernel(
    const float* __restrict__ bx, const float* __restrict__ ax,
    __hip_bfloat16* __restrict__ hbf, float* __restrict__ cs0)
{
  int b = blockIdx.x;             // 0..503
  int t = threadIdx.x;
  float l0 = 0.f, l1 = 0.f;
  for (int q = 0; q < 32; ++q) {
    int row = b * 32 + q;
    int g = row >= NP1;
    int r = row - g * NP1;
    float v = 0.f;
    if (r < NNODES) {
      v = (g ? ax : bx)[(size_t)r * H + t];
      if (g) l1 += v; else l0 += v;
    }
    hbf[(size_t)row * H + t] = __float2bfloat16(v);
  }
  if (l0 != 0.f) atomicAdd(&cs0[t], l0);
  if (l1 != 0.f) atomicAdd(&cs0[256 + t], l1);
}

// ----- hagg_bf = bf16(A @ h): wave-per-row gather, XCD-pinned by graph half --------
// Each row gathers only from its own graph's h (8001 rows x 512 B = 4.096 MB =
// fits one XCD's 4 MiB L2). XCD = blockIdx%8 (round-robin): XCDs 0-3 take graph b,
// 4-7 take graph a, so each XCD's gathers hit its own warm L2.
__global__ __launch_bounds__(256) void spmm_kernel(
    const unsigned short* __restrict__ hbf, unsigned short* __restrict__ haggbf,
    const int* __restrict__ counts, const int* __restrict__ colidx,
    const float* __restrict__ cs)
{
  int w = threadIdx.x >> 6, l = threadIdx.x & 63;
  int B = blockIdx.x;             // grid 4096
  int g = (B & 7) >= 4;           // graph half by XCD
  int j = (B >> 3) * 4 + (B & 3); // 0..2047 within half
  int r = j * 4 + w;              // row within graph, 0..8191
  if (r > NNODES) return;         // valid rows 0..8000 (8000 = supernode)
  int b = g * NP1 + r;
  size_t outoff = (size_t)b * H + l * 4;
  if (r == NNODES) {
    float4 v = *(const float4*)&cs[g * H + l * 4];
    ushort4 o; o.x = f2bl(v.x); o.y = f2bl(v.y); o.z = f2bl(v.z); o.w = f2bl(v.w);
    *(ushort4*)(haggbf + outoff) = o;
    return;
  }
  int rb = g * NNODES + r;
  int cnt = counts[rb];
  const int* cols = colidx + (size_t)rb * CAP;
  const unsigned short* hg = hbf + (size_t)g * NP1 * H;
  float a0 = 0.f, a1 = 0.f, a2 = 0.f, a3 = 0.f;
  int k = 0;
  for (; k + 4 <= cnt; k += 4) {
    int c0 = cols[k], c1 = cols[k+1], c2 = cols[k+2], c3 = cols[k+3];
    uint2 x0 = *(const uint2*)(hg + (size_t)c0 * H + l * 4);
    uint2 x1 = *(const uint2*)(hg + (size_t)c1 * H + l * 4);
    uint2 x2 = *(const uint2*)(hg + (size_t)c2 * H + l * 4);
    uint2 x3 = *(const uint2*)(hg + (size_t)c3 * H + l * 4);
    a0 += bl2f(x0.x & 0xffff) + bl2f(x1.x & 0xffff) + bl2f(x2.x & 0xffff) + bl2f(x3.x & 0xffff);
    a1 += bl2f(x0.x >> 16)    + bl2f(x1.x >> 16)    + bl2f(x2.x >> 16)    + bl2f(x3.x >> 16);
    a2 += bl2f(x0.y & 0xffff) + bl2f(x1.y & 0xffff) + bl2f(x2.y & 0xffff) + bl2f(x3.y & 0xffff);
    a3 += bl2f(x0.y >> 16)    + bl2f(x1.y >> 16)    + bl2f(x2.y >> 16)    + bl2f(x3.y >> 16);
  }
  for (; k < cnt; ++k) {
    uint2 x = *(const uint2*)(hg + (size_t)cols[k] * H + l * 4);
    a0 += bl2f(x.x & 0xffff); a1 += bl2f(x.x >> 16);
    a2 += bl2f(x.y & 0xffff); a3 += bl2f(x.y >> 16);
  }
  ushort4 o; o.x = f2bl(a0); o.y = f2bl(a1); o.z = f2bl(a2); o.w = f2bl(a3);
  *(ushort4*)(haggbf + outoff) = o;
}

// ------- fused [hagg|h] @ Wbig2^T (bf16 MFMA, K=512, BK=64) + GRU epilogue ---------
// 256 rows x 32 units, B-tile 96 rows (n-packed). XCD-pinned grid 512. (round 8)
__global__ __launch_bounds__(256, 2) void fused_gemm_gru_kernel(
    const __hip_bfloat16* __restrict__ haggbf, const __hip_bfloat16* __restrict__ hin,
    const __hip_bfloat16* __restrict__ Wbig2, const float* __restrict__ degf,
    const float* __restrict__ bc, const float* __restrict__ bih,
    const float* __restrict__ bhh,
    __hip_bfloat16* __restrict__ hout, float* __restrict__ cs_next)
{
  __shared__ __align__(16) short lsA[256 * 64];   // 32 KB
  __shared__ __align__(16) short lsB[96 * 64];    // 12 KB
  int bidx = blockIdx.x;                   // 0..511
  int ct = bidx >> 6;                      // 0..7
  int m_i = bidx & 63;                     // 0..63 (63 == idle pad)
  if (m_i >= 63) return;
  int m0 = m_i * 256;
  const short* Bbase = (const short*)Wbig2 + (size_t)ct * 96 * 512;
  const short* Ai = (const short*)haggbf;
  const short* Ah = (const short*)hin;
  const unsigned short* hin_us = (const unsigned short*)hin;
  int t = threadIdx.x;
  int w = t >> 6, l = t & 63;
  int lr = l >> 3;        // staging: row within 8-row group
  int lc = l & 7;         // staging: chunk slot (16 B)
  int wm = (w & 1) * 128, uh = w >> 1;
  int q = l >> 4, lm = l & 15;
  floatx4 acc[8][4] = {};

  for (int ks = 0; ks < 8; ++ks) {
    int k0 = ks * 64;
    bool ihalf = ks < 4;
    const short* Asrc = ihalf ? Ai : Ah;
    int ka = k0 & 255;
    #pragma unroll
    for (int j = 0; j < 8; ++j) {
      int r = w * 64 + j * 8 + lr;
      int sc = lc ^ (r & 7);
      const short* ga = Asrc + (size_t)(m0 + r) * H + ka + sc * 8;
      short* la = lsA + (w * 64 + j * 8) * 64;
      __builtin_amdgcn_global_load_lds((const __attribute__((address_space(1))) void*)ga,
                                       (__attribute__((address_space(3))) void*)la, 16, 0, 0);
    }
    #pragma unroll
    for (int j = 0; j < 3; ++j) {
      int r = w * 24 + j * 8 + lr;
      int sc = lc ^ (r & 7);
      const short* gb = Bbase + (size_t)r * 512 + k0 + sc * 8;
      short* lb = lsB + (w * 24 + j * 8) * 64;
      __builtin_amdgcn_global_load_lds((const __attribute__((address_space(1))) void*)gb,
                                       (__attribute__((address_space(3))) void*)lb, 16, 0, 0);
    }
    __syncthreads();
    #pragma unroll
    for (int kh = 0; kh < 2; ++kh) {
      int kc = kh * 4 + q;
      short8 bfr[3];
      #pragma unroll
      for (int jj = 0; jj < 3; ++jj) {
        int n = (jj * 2 + uh) * 16 + lm;
        bfr[jj] = *(const short8*)&lsB[n * 64 + (kc ^ (n & 7)) * 8];
      }
      #pragma unroll
      for (int i = 0; i < 8; ++i) {
        int m = wm + i * 16 + lm;
        short8 af = *(const short8*)&lsA[m * 64 + (kc ^ (m & 7)) * 8];
        acc[i][0] = __builtin_amdgcn_mfma_f32_16x16x32_bf16(af, bfr[0], acc[i][0], 0, 0, 0);
        acc[i][1] = __builtin_amdgcn_mfma_f32_16x16x32_bf16(af, bfr[1], acc[i][1], 0, 0, 0);
        if (ihalf)
          acc[i][2] = __builtin_amdgcn_mfma_f32_16x16x32_bf16(af, bfr[2], acc[i][2], 0, 0, 0);
        else
          acc[i][3] = __builtin_amdgcn_mfma_f32_16x16x32_bf16(af, bfr[2], acc[i][3], 0, 0, 0);
      }
    }
    __syncthreads();
  }

  // ---- GRU epilogue ----
  int c = ct * 32 + uh * 16 + lm;
  float bcr = bc[c], bcz = bc[256 + c], bcn = bc[512 + c];
  float br  = bih[c] + bhh[c];
  float bz  = bih[256 + c] + bhh[256 + c];
  float bin = bih[512 + c];
  float bhn = bhh[512 + c];
  float lu0 = 0.f, lu1 = 0.f;
  #pragma unroll
  for (int i = 0; i < 8; ++i) {
    int row0 = m0 + wm + i * 16 + q * 4;
    float4 dg = *(const float4*)&degf[row0];
    #pragma unroll
    for (int reg = 0; reg < 4; ++reg) {
      int row = row0 + reg;
      float deg = (&dg.x)[reg];
      float rg = sigf(acc[i][0][reg] + deg * bcr + br);
      float z  = sigf(acc[i][1][reg] + deg * bcz + bz);
      float n  = tanhf_fast(acc[i][2][reg] + deg * bcn + bin + rg * (acc[i][3][reg] + bhn));
      size_t hoff = (size_t)row * H + c;
      float hp = bl2f(hin_us[hoff]);
      float hnew = (1.f - z) * n + z * hp;
      hout[hoff] = __float2bfloat16(hnew);
      if (row < NP1) { if (row < NNODES) lu0 += hnew; }
      else { if (row - NP1 < NNODES) lu1 += hnew; }
    }
  }
  lu0 += __shfl_down(lu0, 32); lu0 += __shfl_down(lu0, 16);
  lu1 += __shfl_down(lu1, 32); lu1 += __shfl_down(lu1, 16);
  if (q == 0) {
    if (lu0 != 0.f) atomicAdd(&cs_next[c], lu0);
    if (lu1 != 0.f) atomicAdd(&cs_next[256 + c], lu1);
  }
}

// ---------------- final logits + log_softmax (bf16 h state) ------------------------
__global__ __launch_bounds__(256) void final_kernel(
    const unsigned short* __restrict__ hbf, const float* __restrict__ Wfc,
    const float* __restrict__ bfc, float* __restrict__ out)
{
  __shared__ float red0[256];
  __shared__ float red1[256];
  int t = threadIdx.x;
  float sn0 = bl2f(hbf[(size_t)NNODES * H + t]);
  float sn1 = bl2f(hbf[((size_t)NP1 + NNODES) * H + t]);
  red0[t] = sn0 * Wfc[t]       + sn1 * Wfc[H + t];
  red1[t] = sn0 * Wfc[512 + t] + sn1 * Wfc[512 + H + t];
  __syncthreads();
  for (int s = 128; s > 0; s >>= 1) {
    if (t < s) { red0[t] += red0[t + s]; red1[t] += red1[t + s]; }
    __syncthreads();
  }
  if (t == 0) {
    float l0 = red0[0] + bfc[0], l1 = red1[0] + bfc[1];
    float m = fmaxf(l0, l1);
    float lse = m + logf(expf(l0 - m) + expf(l1 - m));
    out[0] = l0 - lse;
    out[1] = l1 - lse;
  }
}

extern "C" void kernel_launch(void* const* d_in, const int* in_sizes, int n_in,
                              void* d_out, int out_size, void* d_ws, size_t ws_size,
                              hipStream_t stream) {
  const float* b_x   = (const float*)d_in[0];
  const float* b_adj = (const float*)d_in[1];
  const float* a_x   = (const float*)d_in[2];
  const float* a_adj = (const float*)d_in[3];
  const float* Wlin  = (const float*)d_in[4];
  const float* blin  = (const float*)d_in[5];
  const float* Wih   = (const float*)d_in[6];
  const float* bih   = (const float*)d_in[7];
  const float* Whh   = (const float*)d_in[8];
  const float* bhh   = (const float*)d_in[9];
  const float* Wfc   = (const float*)d_in[10];
  const float* bfc   = (const float*)d_in[11];
  float* out = (float*)d_out;

  char* ws = (char*)d_ws;
  size_t off = 0;
  auto alloc = [&](size_t bytes) {
    void* p = ws + off;
    off += (bytes + 255) & ~(size_t)255;
    return p;
  };
  __hip_bfloat16* hbf0   = (__hip_bfloat16*)alloc((size_t)MPAD * H * 2);   // 8.3 MB
  __hip_bfloat16* hbf1   = (__hip_bfloat16*)alloc((size_t)MPAD * H * 2);   // 8.3 MB
  __hip_bfloat16* haggbf = (__hip_bfloat16*)alloc((size_t)MPAD * H * 2);   // 8.3 MB
  __hip_bfloat16* Wbig2  = (__hip_bfloat16*)alloc((size_t)768 * 512 * 2);  // 0.8 MB
  float* bc              = (float*)alloc((size_t)768 * 4);
  int* colidx            = (int*)alloc((size_t)2 * NNODES * CAP * 4);      // 4.1 MB
  int* counts            = (int*)alloc((size_t)2 * NNODES * 4 + 1024);
  float* degf            = (float*)alloc((size_t)MPAD * 4);
  float* cs              = (float*)alloc((size_t)(TSTEPS + 1) * 2 * H * 4);

  hipMemsetAsync(cs, 0, (size_t)(TSTEPS + 1) * 2 * H * 4, stream);

  build_ell_kernel<<<4000, 256, 0, stream>>>(b_adj, a_adj, counts, colidx);
  degf_kernel<<<MPAD / 256, 256, 0, stream>>>(counts, degf);
  weights_kernel<<<768, 256, 0, stream>>>(Wih, Wlin, blin, Whh, Wbig2, bc);
  init_h_kernel<<<NRB, 256, 0, stream>>>(b_x, a_x, hbf0, cs);

  __hip_bfloat16* ping[2] = { hbf0, hbf1 };
  for (int t = 0; t < TSTEPS; ++t) {
    __hip_bfloat16* hin  = ping[t & 1];
    __hip_bfloat16* hout = ping[(t + 1) & 1];
    spmm_kernel<<<4096, 256, 0, stream>>>(
        (const unsigned short*)hin, (unsigned short*)haggbf, counts, colidx, cs + t * 2 * H);
    fused_gemm_gru_kernel<<<512, 256, 0, stream>>>(
        haggbf, hin, Wbig2, degf, bc, bih, bhh, hout, cs + (t + 1) * 2 * H);
  }
  final_kernel<<<1, 256, 0, stream>>>((const unsigned short*)ping[TSTEPS & 1], Wfc, bfc, out);
}